// Round 1
// baseline (319.675 us; speedup 1.0000x reference)
//
#include <hip/hip_runtime.h>
#include <hip/hip_bf16.h>
#include <stdint.h>

#define NUM_CLASSES 10
#define CPC 100              // clauses per class
#define M_CLAUSES 1000
#define D_LITS 1152
#define L_PATCHES 676
#define BATCH 64
#define KMAX 64              // max selected literals per clause (binomial(1152,0.01): P(>64) ~ 0)
#define NW 12                // packed u64 words per (b,d) row

typedef unsigned long long u64;

// ---------------- flag init ----------------
__global__ void zero_flag_kernel(int* flag) { *flag = 0; }

// ---------------- dtype detect for clause_mask ----------------
// Reads the first (M*D) bytes as u32. If the mask was uploaded as int32 {0,1},
// every byte at offset %4 != 0 is zero. If it was uploaded as 1-byte bool,
// ~8.6k of those bytes are 1. Deterministic for the fixed dataset.
__global__ void detect_kernel(const unsigned int* __restrict__ mask_u32, int n_u32,
                              int* __restrict__ flag) {
  int i = blockIdx.x * blockDim.x + threadIdx.x;
  int stride = gridDim.x * blockDim.x;
  int local = 0;
  for (; i < n_u32; i += stride) {
    if (mask_u32[i] & 0xFFFFFF00u) local = 1;
  }
  if (local) atomicOr(flag, 1);
}

// ---------------- clause -> selected-index lists ----------------
__global__ void mask_index_kernel(const void* __restrict__ maskp,
                                  const int* __restrict__ flag,
                                  int* __restrict__ counts,
                                  int* __restrict__ idx) {
  int m = blockIdx.x;
  __shared__ int cnt;
  if (threadIdx.x == 0) cnt = 0;
  __syncthreads();
  bool isbool = (*flag != 0);
  for (int d = threadIdx.x; d < D_LITS; d += blockDim.x) {
    bool sel;
    if (isbool) sel = ((const unsigned char*)maskp)[(size_t)m * D_LITS + d] != 0;
    else        sel = ((const int*)maskp)[(size_t)m * D_LITS + d] != 0;
    if (sel) {
      int p = atomicAdd(&cnt, 1);
      if (p < KMAX) idx[m * KMAX + p] = d;
    }
  }
  __syncthreads();
  if (threadIdx.x == 0) counts[m] = cnt > KMAX ? KMAX : cnt;
}

// ---------------- pack literals into bitplanes ----------------
// One wave per (b,d) row. Lane i loads int4 #(it*64+i); 4 ballots per iter
// produce 4 u64 words. Patch -> bit mapping is a fixed permutation:
// word w = it*4 + comp, bit i  <->  patch it*256 + 4*i + comp.
// Valid-bit masks: words 0..7 all 64 bits; words 8..11 bits 0..40 (41*4*? ->
// int4 indices 128..168 => lanes 0..40 valid, covering patches 512..675).
__global__ __launch_bounds__(256) void pack_kernel(const int* __restrict__ lits,
                                                   u64* __restrict__ packed) {
  int wib  = threadIdx.x >> 6;
  int lane = threadIdx.x & 63;
  int row  = blockIdx.x * 4 + wib;           // 4 waves per block
  if (row >= BATCH * D_LITS) return;
  const int4* src = (const int4*)(lits + (size_t)row * L_PATCHES);
  u64 w[12];
#pragma unroll
  for (int it = 0; it < 3; ++it) {
    int i4 = it * 64 + lane;
    int4 v = make_int4(0, 0, 0, 0);
    if (i4 < (L_PATCHES / 4)) v = src[i4];   // 169 int4 per row
    w[it * 4 + 0] = __ballot(v.x != 0);
    w[it * 4 + 1] = __ballot(v.y != 0);
    w[it * 4 + 2] = __ballot(v.z != 0);
    w[it * 4 + 3] = __ballot(v.w != 0);
  }
  if (lane == 0) {
    ulonglong2* d2 = (ulonglong2*)(packed + (size_t)row * NW);
    d2[0] = make_ulonglong2(w[0],  w[1]);
    d2[1] = make_ulonglong2(w[2],  w[3]);
    d2[2] = make_ulonglong2(w[4],  w[5]);
    d2[3] = make_ulonglong2(w[6],  w[7]);
    d2[4] = make_ulonglong2(w[8],  w[9]);
    d2[5] = make_ulonglong2(w[10], w[11]);
  }
}

// ---------------- clause evaluation + class vote ----------------
__global__ __launch_bounds__(256) void score_kernel(const u64* __restrict__ packed,
                                                    const int* __restrict__ counts,
                                                    const int* __restrict__ idx,
                                                    const float* __restrict__ alpha,
                                                    float* __restrict__ out) {
  int b = blockIdx.x;
  __shared__ float cls[NUM_CLASSES];
  if (threadIdx.x < NUM_CLASSES) cls[threadIdx.x] = 0.f;
  __syncthreads();
  const u64* base = packed + (size_t)b * D_LITS * NW;
  const u64 TAIL = (1ull << 41) - 1;         // valid bits in words 8..11
  for (int m = threadIdx.x; m < M_CLAUSES; m += blockDim.x) {
    int c = counts[m];
    u64 a0 = ~0ull, a1 = ~0ull, a2 = ~0ull, a3 = ~0ull;
    u64 a4 = ~0ull, a5 = ~0ull, a6 = ~0ull, a7 = ~0ull;
    u64 a8 = TAIL,  a9 = TAIL,  a10 = TAIL, a11 = TAIL;
    const int* il = idx + m * KMAX;
    for (int k = 0; k < c; ++k) {
      const ulonglong2* row = (const ulonglong2*)(base + (size_t)il[k] * NW);
      ulonglong2 r0 = row[0], r1 = row[1], r2 = row[2];
      ulonglong2 r3 = row[3], r4 = row[4], r5 = row[5];
      a0 &= r0.x;  a1 &= r0.y;  a2 &= r1.x;  a3 &= r1.y;
      a4 &= r2.x;  a5 &= r2.y;  a6 &= r3.x;  a7 &= r3.y;
      a8 &= r4.x;  a9 &= r4.y;  a10 &= r5.x; a11 &= r5.y;
    }
    u64 any = (a0 | a1 | a2 | a3) | (a4 | a5 | a6 | a7) | (a8 | a9 | a10 | a11);
    if (any) {
      float a = alpha[m];
      int cid = m / CPC;
      int q = m - cid * CPC;
      atomicAdd(&cls[cid], (q < (CPC / 2)) ? a : -a);
    }
  }
  __syncthreads();
  if (threadIdx.x < NUM_CLASSES) out[b * NUM_CLASSES + threadIdx.x] = cls[threadIdx.x];
}

extern "C" void kernel_launch(void* const* d_in, const int* in_sizes, int n_in,
                              void* d_out, int out_size, void* d_ws, size_t ws_size,
                              hipStream_t stream) {
  const int*   lits  = (const int*)d_in[0];     // [B, D, L] int32 {0,1}
  const void*  mask  = d_in[1];                 // [M, D] bool (int8 or int32 — detected)
  const float* alpha = (const float*)d_in[2];   // [M] f32
  float* out = (float*)d_out;                   // [B, 10] f32

  char* ws = (char*)d_ws;
  int*  flag   = (int*)ws;                      // 4 B
  int*  counts = (int*)(ws + 256);              // 1000 * 4 B
  int*  idx    = (int*)(ws + 4352);             // 1000 * 64 * 4 B
  u64*  packed = (u64*)(ws + 262144);           // 73728 * 12 * 8 B = 7.08 MB

  zero_flag_kernel<<<1, 1, 0, stream>>>(flag);
  detect_kernel<<<512, 256, 0, stream>>>((const unsigned int*)mask,
                                         (M_CLAUSES * D_LITS) / 4, flag);
  mask_index_kernel<<<M_CLAUSES, 256, 0, stream>>>(mask, flag, counts, idx);
  pack_kernel<<<(BATCH * D_LITS) / 4, 256, 0, stream>>>(lits, packed);
  score_kernel<<<BATCH, 256, 0, stream>>>(packed, counts, idx, alpha, out);
}

// Round 2
// 296.913 us; speedup vs baseline: 1.0767x; 1.0767x over previous
//
#include <hip/hip_runtime.h>
#include <hip/hip_bf16.h>
#include <stdint.h>

#define NUM_CLASSES 10
#define CPC 100              // clauses per class
#define M_CLAUSES 1000
#define D_LITS 1152
#define L_PATCHES 676
#define BATCH 64
#define KMAX 64              // max selected literals per clause; P(Binom(1152,.01)>64) ~ 0
#define NPACK_BLK 18432      // BATCH*D_LITS/4 rows, 4 waves/block
#define NDET_BLK 64

typedef unsigned long long u64;

// ---------------- pack literals into bitplanes, layout [d][pair][b] ----------
// One wave per (b,d) row. Lane i loads int4 #(it*64+i); 4 ballots/iter give 4
// wave-uniform u64 words. Bit mapping: word it*4+comp, bit lane <-> patch
// it*256+4*lane+comp (any fixed permutation is valid for AND/OR semantics).
// Words 8..11 have valid bits 0..40 only (patches 512..675).
// Output layout: packed[(d*6 + j)*64 + b] = ulonglong2{word 2j, word 2j+1}
// so a clause-eval wave (lane = b) reads coalesced 1 KB per (d,j).
// Extra trailing blocks: 64 dtype-detect blocks (scan clause_mask bytes) and
// one block zeroing d_out (runs before score in stream order).
__global__ __launch_bounds__(256) void pack_kernel(
    const int* __restrict__ lits,
    const unsigned int* __restrict__ mask_u32,
    ulonglong2* __restrict__ packed,
    int* __restrict__ flags,
    float* __restrict__ out)
{
  int bid = blockIdx.x;
  if (bid < NPACK_BLK) {
    int wib  = threadIdx.x >> 6;
    int lane = threadIdx.x & 63;
    int row  = bid * 4 + wib;                 // row = b*D + d
    int b = row / D_LITS;
    int d = row - b * D_LITS;
    const int4* src = (const int4*)(lits + (size_t)row * L_PATCHES);
    u64 w0,w1,w2,w3,w4,w5,w6,w7,w8,w9,w10,w11;
    {
      int4 v = src[lane];                     // it=0: i4 = lane < 169 always
      w0 = __ballot(v.x != 0); w1 = __ballot(v.y != 0);
      w2 = __ballot(v.z != 0); w3 = __ballot(v.w != 0);
    }
    {
      int4 v = src[64 + lane];                // it=1
      w4 = __ballot(v.x != 0); w5 = __ballot(v.y != 0);
      w6 = __ballot(v.z != 0); w7 = __ballot(v.w != 0);
    }
    {
      int4 v = make_int4(0,0,0,0);
      if (lane < 41) v = src[128 + lane];     // it=2: 169 int4 per row
      w8 = __ballot(v.x != 0); w9 = __ballot(v.y != 0);
      w10 = __ballot(v.z != 0); w11 = __ballot(v.w != 0);
    }
    ulonglong2* dst = packed + (size_t)d * 6 * 64 + b;
    if      (lane == 0) dst[0*64] = make_ulonglong2(w0,  w1);
    else if (lane == 1) dst[1*64] = make_ulonglong2(w2,  w3);
    else if (lane == 2) dst[2*64] = make_ulonglong2(w4,  w5);
    else if (lane == 3) dst[3*64] = make_ulonglong2(w6,  w7);
    else if (lane == 4) dst[4*64] = make_ulonglong2(w8,  w9);
    else if (lane == 5) dst[5*64] = make_ulonglong2(w10, w11);
  } else if (bid < NPACK_BLK + NDET_BLK) {
    // dtype detect: int32 {0,1} mask has all bytes at offset%4!=0 equal to 0;
    // byte-bool mask has ~8.6k nonzero odd-offset bytes. Scan first M*D bytes.
    int db = bid - NPACK_BLK;
    __shared__ int sfound;
    if (threadIdx.x == 0) sfound = 0;
    __syncthreads();
    int n = (M_CLAUSES * D_LITS) / 4;
    int found = 0;
    for (int i = db * 256 + threadIdx.x; i < n; i += NDET_BLK * 256)
      if (mask_u32[i] & 0xFFFFFF00u) found = 1;
    if (found) sfound = 1;                    // benign race
    __syncthreads();
    if (threadIdx.x == 0) flags[db] = sfound;
  } else {
    // zero d_out (poisoned 0xAA by harness; score atomically accumulates)
    for (int i = threadIdx.x; i < BATCH * NUM_CLASSES; i += 256) out[i] = 0.f;
  }
}

// ---------------- clause evaluation + class vote -----------------------------
// One wave per clause m; lane = batch element b. Build the selected-literal
// list in LDS from clause_mask, then AND coalesced [d][j][b] bitplanes.
__global__ __launch_bounds__(64) void score_kernel(
    const ulonglong2* __restrict__ packed,
    const void* __restrict__ maskp,
    const int* __restrict__ flags,
    const float* __restrict__ alpha,
    float* __restrict__ out)
{
  int m   = blockIdx.x;
  int tid = threadIdx.x;
  __shared__ int list[KMAX];
  __shared__ int cnt;
  __shared__ int isbool;
  if (tid == 0) {
    cnt = 0;
    int f = 0;
#pragma unroll
    for (int i = 0; i < NDET_BLK; ++i) f |= flags[i];
    isbool = f;
  }
  __syncthreads();
  bool ib = (isbool != 0);
  for (int d = tid; d < D_LITS; d += 64) {
    bool sel = ib ? (((const unsigned char*)maskp)[(size_t)m * D_LITS + d] != 0)
                  : (((const int*)maskp)[(size_t)m * D_LITS + d] != 0);
    if (sel) { int p = atomicAdd(&cnt, 1); if (p < KMAX) list[p] = d; }
  }
  __syncthreads();
  int c = cnt; if (c > KMAX) c = KMAX;
  const u64 TAIL = (1ull << 41) - 1;          // valid bits of words 8..11
  u64 a0=~0ull,a1=~0ull,a2=~0ull,a3=~0ull,a4=~0ull,a5=~0ull,a6=~0ull,a7=~0ull;
  u64 a8=TAIL, a9=TAIL, a10=TAIL, a11=TAIL;
  for (int k = 0; k < c; ++k) {
    int d = list[k];                          // wave-uniform LDS broadcast
    const ulonglong2* p = packed + (size_t)d * 6 * 64 + tid;
    ulonglong2 r0 = p[0*64], r1 = p[1*64], r2 = p[2*64];
    ulonglong2 r3 = p[3*64], r4 = p[4*64], r5 = p[5*64];
    a0 &= r0.x;  a1 &= r0.y;  a2 &= r1.x;  a3 &= r1.y;
    a4 &= r2.x;  a5 &= r2.y;  a6 &= r3.x;  a7 &= r3.y;
    a8 &= r4.x;  a9 &= r4.y;  a10 &= r5.x; a11 &= r5.y;
  }
  u64 any = (a0|a1|a2|a3)|(a4|a5|a6|a7)|(a8|a9|a10|a11);
  if (any) {
    float a = alpha[m];
    int cid = m / CPC;
    float v = ((m - cid * CPC) < (CPC / 2)) ? a : -a;
    atomicAdd(&out[tid * NUM_CLASSES + cid], v);
  }
}

extern "C" void kernel_launch(void* const* d_in, const int* in_sizes, int n_in,
                              void* d_out, int out_size, void* d_ws, size_t ws_size,
                              hipStream_t stream) {
  const int*   lits  = (const int*)d_in[0];   // [B, D, L] int32 {0,1}
  const void*  mask  = d_in[1];               // [M, D] bool (int8 or int32 — detected)
  const float* alpha = (const float*)d_in[2]; // [M] f32
  float* out = (float*)d_out;                 // [B, 10] f32

  char* ws = (char*)d_ws;
  int*        flags  = (int*)ws;              // 64 * 4 B
  ulonglong2* packed = (ulonglong2*)(ws + 4096); // D*6*64 * 16 B = 7.08 MB

  pack_kernel<<<NPACK_BLK + NDET_BLK + 1, 256, 0, stream>>>(
      lits, (const unsigned int*)mask, packed, flags, out);
  score_kernel<<<M_CLAUSES, 64, 0, stream>>>(packed, mask, flags, alpha, out);
}

// Round 3
// 279.864 us; speedup vs baseline: 1.1422x; 1.0609x over previous
//
#include <hip/hip_runtime.h>
#include <hip/hip_bf16.h>
#include <stdint.h>

#define NUM_CLASSES 10
#define CPC 100              // clauses per class
#define M_CLAUSES 1000
#define D_LITS 1152
#define L_PATCHES 676
#define BATCH 64
#define KMAX 64              // max selected literals per clause; P(Binom(1152,.01)>64) ~ 0
#define WPB 8                // waves per pack block
#define NPACK_BLK 9216       // BATCH*D_LITS / WPB
#define NDET_BLK 64

typedef unsigned long long u64;

static __device__ __forceinline__ int4 nt_load_int4(const int4* p) {
  int4 r;
  r.x = __builtin_nontemporal_load(&((const int*)p)[0]);
  r.y = __builtin_nontemporal_load(&((const int*)p)[1]);
  r.z = __builtin_nontemporal_load(&((const int*)p)[2]);
  r.w = __builtin_nontemporal_load(&((const int*)p)[3]);
  return r;
}

// ---------------- pack literals into bitplanes, layout [d][pair][b] ----------
// One wave per (b,d) row. Lane i loads int4 #(seg*64+i); 4 ballots/segment give
// 4 wave-uniform u64 words. Bit mapping (fixed permutation, AND/OR-invariant):
// word seg*4+comp, bit lane <-> patch seg*256 + 4*lane + comp.
// Words 8..11 valid bits 0..40 only (patches 512..675 = 164 = 41*4).
// Output: packed[(d*6 + j)*64 + b] = ulonglong2{word 2j, word 2j+1}, so a
// score wave (lane = b) reads coalesced 1 KB per (d,j).
// Trailing blocks: 64 dtype-detect blocks + 1 block zeroing d_out.
__global__ __launch_bounds__(512) void pack_kernel(
    const int* __restrict__ lits,
    const unsigned int* __restrict__ mask_u32,
    ulonglong2* __restrict__ packed,
    int* __restrict__ flags,
    float* __restrict__ out)
{
  int bid = blockIdx.x;
  if (bid < NPACK_BLK) {
    int wib  = threadIdx.x >> 6;
    int lane = threadIdx.x & 63;
    int row  = bid * WPB + wib;               // row = b*D + d
    int b = row / D_LITS;
    int d = row - b * D_LITS;
    const int4* src = (const int4*)(lits + (size_t)row * L_PATCHES);
    u64 w0,w1,w2,w3,w4,w5,w6,w7,w8,w9,w10,w11;
    {
      int4 v = nt_load_int4(src + lane);            // seg 0 (int4 0..63)
      w0 = __ballot(v.x != 0); w1 = __ballot(v.y != 0);
      w2 = __ballot(v.z != 0); w3 = __ballot(v.w != 0);
    }
    {
      int4 v = nt_load_int4(src + 64 + lane);       // seg 1 (int4 64..127)
      w4 = __ballot(v.x != 0); w5 = __ballot(v.y != 0);
      w6 = __ballot(v.z != 0); w7 = __ballot(v.w != 0);
    }
    {
      int4 v = make_int4(0,0,0,0);
      if (lane < 41) v = nt_load_int4(src + 128 + lane); // seg 2 (169 int4/row)
      w8 = __ballot(v.x != 0); w9 = __ballot(v.y != 0);
      w10 = __ballot(v.z != 0); w11 = __ballot(v.w != 0);
    }
    // lane j (<6) stores pair (w[2j], w[2j+1]); words are wave-uniform, so the
    // selection chain compiles to cndmasks — a single store instruction.
    u64 lo = w0, hi = w1;
    if (lane == 1) { lo = w2;  hi = w3;  }
    if (lane == 2) { lo = w4;  hi = w5;  }
    if (lane == 3) { lo = w6;  hi = w7;  }
    if (lane == 4) { lo = w8;  hi = w9;  }
    if (lane == 5) { lo = w10; hi = w11; }
    if (lane < 6)
      packed[(size_t)d * 384 + (size_t)lane * 64 + b] = make_ulonglong2(lo, hi);
  } else if (bid < NPACK_BLK + NDET_BLK) {
    // dtype detect: an int32 {0,1} mask has every byte at offset%4!=0 equal 0;
    // a byte-bool mask has ~8.6k nonzero ones. Scan first M*D bytes as u32.
    int db = bid - NPACK_BLK;
    __shared__ int sfound;
    if (threadIdx.x == 0) sfound = 0;
    __syncthreads();
    int n = (M_CLAUSES * D_LITS) / 4;
    int found = 0;
    for (int i = db * 512 + threadIdx.x; i < n; i += NDET_BLK * 512)
      if (__builtin_nontemporal_load(mask_u32 + i) & 0xFFFFFF00u) found = 1;
    if (found) sfound = 1;                    // benign race
    __syncthreads();
    if (threadIdx.x == 0) flags[db] = sfound;
  } else {
    // zero d_out (poisoned 0xAA by harness; score atomically accumulates).
    // Kernel boundary guarantees completion before score's atomics.
    if (threadIdx.x < BATCH * NUM_CLASSES) out[threadIdx.x] = 0.f;
  }
}

// ---------------- clause evaluation + class vote -----------------------------
// One wave per clause m; lane = batch element b. Selected-literal list built in
// LDS from clause_mask, then AND coalesced [d][j][b] bitplanes (L2-resident).
__global__ __launch_bounds__(64) void score_kernel(
    const ulonglong2* __restrict__ packed,
    const void* __restrict__ maskp,
    const int* __restrict__ flags,
    const float* __restrict__ alpha,
    float* __restrict__ out)
{
  int m   = blockIdx.x;
  int tid = threadIdx.x;
  __shared__ int list[KMAX];
  __shared__ int cnt;
  __shared__ int isbool;
  if (tid == 0) {
    cnt = 0;
    int f = 0;
#pragma unroll
    for (int i = 0; i < NDET_BLK; ++i) f |= flags[i];
    isbool = f;
  }
  __syncthreads();
  if (isbool) {
    // byte-bool mask: lane reads 4 bytes per round, 1152/256 = 4.5 rounds
    const unsigned int* mrow = (const unsigned int*)maskp + (size_t)m * (D_LITS / 4);
    for (int r = 0; r < 5; ++r) {
      int i = r * 64 + tid;                   // u32 index within row (288 total)
      if (i < D_LITS / 4) {
        unsigned int v = mrow[i];
        if (v) {
#pragma unroll
          for (int c4 = 0; c4 < 4; ++c4)
            if ((v >> (8 * c4)) & 0xFF) { int p = atomicAdd(&cnt, 1); if (p < KMAX) list[p] = i * 4 + c4; }
        }
      }
    }
  } else {
    // int32 mask: lane reads int4 per round, 288 int4 per row -> 4.5 rounds
    const int4* mrow = (const int4*)((const int*)maskp + (size_t)m * D_LITS);
    for (int r = 0; r < 5; ++r) {
      int i = r * 64 + tid;
      if (i < D_LITS / 4) {
        int4 v = mrow[i];
        if (v.x) { int p = atomicAdd(&cnt, 1); if (p < KMAX) list[p] = i * 4 + 0; }
        if (v.y) { int p = atomicAdd(&cnt, 1); if (p < KMAX) list[p] = i * 4 + 1; }
        if (v.z) { int p = atomicAdd(&cnt, 1); if (p < KMAX) list[p] = i * 4 + 2; }
        if (v.w) { int p = atomicAdd(&cnt, 1); if (p < KMAX) list[p] = i * 4 + 3; }
      }
    }
  }
  __syncthreads();
  int c = cnt; if (c > KMAX) c = KMAX;
  const u64 TAIL = (1ull << 41) - 1;          // valid bits of words 8..11
  u64 a0=~0ull,a1=~0ull,a2=~0ull,a3=~0ull,a4=~0ull,a5=~0ull,a6=~0ull,a7=~0ull;
  u64 a8=TAIL, a9=TAIL, a10=TAIL, a11=TAIL;
  int k = 0;
  for (; k + 2 <= c; k += 2) {                // 2 d's in flight: 12 x 1KB loads
    const ulonglong2* p0 = packed + (size_t)list[k]     * 384 + tid;
    const ulonglong2* p1 = packed + (size_t)list[k + 1] * 384 + tid;
    ulonglong2 r0 = p0[0], r1 = p0[64], r2 = p0[128];
    ulonglong2 r3 = p0[192], r4 = p0[256], r5 = p0[320];
    ulonglong2 s0 = p1[0], s1 = p1[64], s2 = p1[128];
    ulonglong2 s3 = p1[192], s4 = p1[256], s5 = p1[320];
    a0 &= r0.x & s0.x;  a1 &= r0.y & s0.y;  a2 &= r1.x & s1.x;  a3 &= r1.y & s1.y;
    a4 &= r2.x & s2.x;  a5 &= r2.y & s2.y;  a6 &= r3.x & s3.x;  a7 &= r3.y & s3.y;
    a8 &= r4.x & s4.x;  a9 &= r4.y & s4.y;  a10 &= r5.x & s5.x; a11 &= r5.y & s5.y;
  }
  if (k < c) {
    const ulonglong2* p0 = packed + (size_t)list[k] * 384 + tid;
    ulonglong2 r0 = p0[0], r1 = p0[64], r2 = p0[128];
    ulonglong2 r3 = p0[192], r4 = p0[256], r5 = p0[320];
    a0 &= r0.x;  a1 &= r0.y;  a2 &= r1.x;  a3 &= r1.y;
    a4 &= r2.x;  a5 &= r2.y;  a6 &= r3.x;  a7 &= r3.y;
    a8 &= r4.x;  a9 &= r4.y;  a10 &= r5.x; a11 &= r5.y;
  }
  u64 any = (a0|a1|a2|a3)|(a4|a5|a6|a7)|(a8|a9|a10|a11);
  if (any) {
    float a = alpha[m];
    int cid = m / CPC;
    float v = ((m - cid * CPC) < (CPC / 2)) ? a : -a;
    atomicAdd(&out[tid * NUM_CLASSES + cid], v);
  }
}

extern "C" void kernel_launch(void* const* d_in, const int* in_sizes, int n_in,
                              void* d_out, int out_size, void* d_ws, size_t ws_size,
                              hipStream_t stream) {
  const int*   lits  = (const int*)d_in[0];   // [B, D, L] int32 {0,1}
  const void*  mask  = d_in[1];               // [M, D] bool (int8 or int32 — detected)
  const float* alpha = (const float*)d_in[2]; // [M] f32
  float* out = (float*)d_out;                 // [B, 10] f32

  char* ws = (char*)d_ws;
  int*        flags  = (int*)ws;              // 64 * 4 B
  ulonglong2* packed = (ulonglong2*)(ws + 4096); // D*6*64 * 16 B = 7.08 MB

  pack_kernel<<<NPACK_BLK + NDET_BLK + 1, 512, 0, stream>>>(
      lits, (const unsigned int*)mask, packed, flags, out);
  score_kernel<<<M_CLAUSES, 64, 0, stream>>>(packed, mask, flags, alpha, out);
}